// Round 6
// baseline (102.040 us; speedup 1.0000x reference)
//
#include <hip/hip_runtime.h>

// SpatialCrossAttention (BEVFormer) — 4 kernels:
//  K1 vproj : value @ Wv + bv -> vhw bf16        (register-tiled VALU GEMM)
//  K2 qproj : (query+query_pos) @ [Wo|Wa] -> off_raw, logits (register-tiled GEMM)
//  K3 attn  : mask + softmax + weight/offset precompute + bf16 gather -> slots bf16
//  K4 oproj : slots @ Wp + bp + query -> out     (register-tiled GEMM + residual)

#define S_DIM 6
#define N_DIM 10000
#define C_DIM 128
#define M_DIM 3680
#define H_DIM 4
#define P_DIM 8
#define DH    32
#define HF    46
#define WF    80

#define G_Q   4
#define NENT  (S_DIM * P_DIM * H_DIM)             // 192
#define VHW_SHORTS (S_DIM * H_DIM * M_DIM * DH)   // 2,826,240

__device__ __forceinline__ float bfl(unsigned u) { return __uint_as_float(u << 16); }
__device__ __forceinline__ float bfh(unsigned u) { return __uint_as_float(u & 0xffff0000u); }
__device__ __forceinline__ float bf1(unsigned short u) { return __uint_as_float(((unsigned)u) << 16); }
__device__ __forceinline__ unsigned short f2bf(float f) {
    unsigned b = __float_as_uint(f);
    b += 0x7FFFu + ((b >> 16) & 1u);   // RNE
    return (unsigned short)(b >> 16);
}

// ---------------------------------------------------------------- K1 vproj
__global__ __launch_bounds__(256) void vproj_kernel(
    const float* __restrict__ value,   // (S*M, C)
    const float* __restrict__ Wv,      // (C, C)
    const float* __restrict__ bv,      // (C)
    unsigned short* __restrict__ vhw)  // (S, H, M, DH) bf16
{
    const int row0 = blockIdx.x * 64;
    const int t = threadIdx.x;
    const int tc = t & 31, tr = t >> 5;
    const int c0 = tc * 4, r0 = tr * 8;
    __shared__ float vs[64][C_DIM];    // 32 KB

    for (int i = t; i < 64 * 32; i += 256) {
        const int row = i >> 5, c4 = (i & 31) * 4;
        *(float4*)&vs[row][c4] = *(const float4*)&value[(size_t)(row0 + row) * C_DIM + c4];
    }
    __syncthreads();

    float acc[8][4];
#pragma unroll
    for (int r = 0; r < 8; ++r)
#pragma unroll
        for (int c = 0; c < 4; ++c) acc[r][c] = 0.f;

    for (int k = 0; k < C_DIM; k += 4) {
        const float4 w0 = *(const float4*)&Wv[(k + 0) * C_DIM + c0];
        const float4 w1 = *(const float4*)&Wv[(k + 1) * C_DIM + c0];
        const float4 w2 = *(const float4*)&Wv[(k + 2) * C_DIM + c0];
        const float4 w3 = *(const float4*)&Wv[(k + 3) * C_DIM + c0];
#pragma unroll
        for (int r = 0; r < 8; ++r) {
            const float4 v = *(const float4*)&vs[r0 + r][k];
            acc[r][0] = fmaf(v.x, w0.x, acc[r][0]);
            acc[r][0] = fmaf(v.y, w1.x, acc[r][0]);
            acc[r][0] = fmaf(v.z, w2.x, acc[r][0]);
            acc[r][0] = fmaf(v.w, w3.x, acc[r][0]);
            acc[r][1] = fmaf(v.x, w0.y, acc[r][1]);
            acc[r][1] = fmaf(v.y, w1.y, acc[r][1]);
            acc[r][1] = fmaf(v.z, w2.y, acc[r][1]);
            acc[r][1] = fmaf(v.w, w3.y, acc[r][1]);
            acc[r][2] = fmaf(v.x, w0.z, acc[r][2]);
            acc[r][2] = fmaf(v.y, w1.z, acc[r][2]);
            acc[r][2] = fmaf(v.z, w2.z, acc[r][2]);
            acc[r][2] = fmaf(v.w, w3.z, acc[r][2]);
            acc[r][3] = fmaf(v.x, w0.w, acc[r][3]);
            acc[r][3] = fmaf(v.y, w1.w, acc[r][3]);
            acc[r][3] = fmaf(v.z, w2.w, acc[r][3]);
            acc[r][3] = fmaf(v.w, w3.w, acc[r][3]);
        }
    }

    const float4 bb = *(const float4*)&bv[c0];
    const int h = c0 >> 5, dh0 = c0 & 31;
#pragma unroll
    for (int r = 0; r < 8; ++r) {
        const int row = row0 + r0 + r;
        const int s = row / M_DIM, m = row - s * M_DIM;
        ushort4 o;
        o.x = f2bf(acc[r][0] + bb.x);
        o.y = f2bf(acc[r][1] + bb.y);
        o.z = f2bf(acc[r][2] + bb.z);
        o.w = f2bf(acc[r][3] + bb.w);
        *(ushort4*)&vhw[(((size_t)s * H_DIM + h) * M_DIM + m) * DH + dh0] = o;
    }
}

// ---------------------------------------------------------------- K2 qproj
__global__ __launch_bounds__(256) void qproj_kernel(
    const float* __restrict__ query,
    const float* __restrict__ query_pos,
    const float* __restrict__ Wo, const float* __restrict__ bo,   // (C,64),(64)
    const float* __restrict__ Wa, const float* __restrict__ ba,   // (C,32),(32)
    float* __restrict__ off_raw,   // (N,64)
    float* __restrict__ logits)    // (N,32)
{
    const int row0 = blockIdx.x * 64;
    const int t = threadIdx.x;
    const int tc = t & 31, tr = t >> 5;
    const int c0 = tc * 4, r0 = tr * 8;
    __shared__ float qs[64][C_DIM];

    for (int i = t; i < 64 * 32; i += 256) {
        const int row = i >> 5, c4 = (i & 31) * 4;
        int rr = row0 + row; if (rr >= N_DIM) rr = N_DIM - 1;
        const float4 a = *(const float4*)&query[(size_t)rr * C_DIM + c4];
        const float4 b = *(const float4*)&query_pos[(size_t)rr * C_DIM + c4];
        float4 q; q.x = a.x + b.x; q.y = a.y + b.y; q.z = a.z + b.z; q.w = a.w + b.w;
        *(float4*)&qs[row][c4] = q;
    }
    __syncthreads();
    if (tc >= 24) return;   // cols 96..127 unused (no further barriers)

    const bool isWo = (tc < 16);
    float acc[8][4];
#pragma unroll
    for (int r = 0; r < 8; ++r)
#pragma unroll
        for (int c = 0; c < 4; ++c) acc[r][c] = 0.f;

    for (int k = 0; k < C_DIM; k += 4) {
        float4 w0, w1, w2, w3;
        if (isWo) {
            w0 = *(const float4*)&Wo[(k + 0) * 64 + c0];
            w1 = *(const float4*)&Wo[(k + 1) * 64 + c0];
            w2 = *(const float4*)&Wo[(k + 2) * 64 + c0];
            w3 = *(const float4*)&Wo[(k + 3) * 64 + c0];
        } else {
            w0 = *(const float4*)&Wa[(k + 0) * 32 + (c0 - 64)];
            w1 = *(const float4*)&Wa[(k + 1) * 32 + (c0 - 64)];
            w2 = *(const float4*)&Wa[(k + 2) * 32 + (c0 - 64)];
            w3 = *(const float4*)&Wa[(k + 3) * 32 + (c0 - 64)];
        }
#pragma unroll
        for (int r = 0; r < 8; ++r) {
            const float4 v = *(const float4*)&qs[r0 + r][k];
            acc[r][0] = fmaf(v.x, w0.x, acc[r][0]);
            acc[r][0] = fmaf(v.y, w1.x, acc[r][0]);
            acc[r][0] = fmaf(v.z, w2.x, acc[r][0]);
            acc[r][0] = fmaf(v.w, w3.x, acc[r][0]);
            acc[r][1] = fmaf(v.x, w0.y, acc[r][1]);
            acc[r][1] = fmaf(v.y, w1.y, acc[r][1]);
            acc[r][1] = fmaf(v.z, w2.y, acc[r][1]);
            acc[r][1] = fmaf(v.w, w3.y, acc[r][1]);
            acc[r][2] = fmaf(v.x, w0.z, acc[r][2]);
            acc[r][2] = fmaf(v.y, w1.z, acc[r][2]);
            acc[r][2] = fmaf(v.z, w2.z, acc[r][2]);
            acc[r][2] = fmaf(v.w, w3.z, acc[r][2]);
            acc[r][3] = fmaf(v.x, w0.w, acc[r][3]);
            acc[r][3] = fmaf(v.y, w1.w, acc[r][3]);
            acc[r][3] = fmaf(v.z, w2.w, acc[r][3]);
            acc[r][3] = fmaf(v.w, w3.w, acc[r][3]);
        }
    }

#pragma unroll
    for (int r = 0; r < 8; ++r) {
        const int row = row0 + r0 + r;
        if (row >= N_DIM) continue;
        if (isWo) {
            const float4 bb = *(const float4*)&bo[c0];
            float4 o; o.x = acc[r][0] + bb.x; o.y = acc[r][1] + bb.y;
            o.z = acc[r][2] + bb.z; o.w = acc[r][3] + bb.w;
            *(float4*)&off_raw[(size_t)row * 64 + c0] = o;
        } else {
            const float4 bb = *(const float4*)&ba[c0 - 64];
            float4 o; o.x = acc[r][0] + bb.x; o.y = acc[r][1] + bb.y;
            o.z = acc[r][2] + bb.z; o.w = acc[r][3] + bb.w;
            *(float4*)&logits[(size_t)row * 32 + (c0 - 64)] = o;
        }
    }
}

// ---------------------------------------------------------------- K3 attn
__global__ __launch_bounds__(256) void attn_kernel(
    const unsigned short* __restrict__ vhw,   // (S,H,M,DH) bf16
    const float* __restrict__ off_raw,  // (N,64)
    const float* __restrict__ logits,   // (N,32)
    const float* __restrict__ refpts,   // (S,1,N,4,2)
    const void* __restrict__ bev_mask,  // (S,1,N,4) bool/int32
    const void* __restrict__ sshapes,   // int probe
    unsigned short* __restrict__ slots) // (N,C) bf16
{
    const int n0 = blockIdx.x * G_Q;
    const int t = threadIdx.x;          // 256

    __shared__ float   s_off[G_Q][64];                    // 1 KB
    __shared__ float   s_attw[G_Q][32];                   // 0.5 KB
    __shared__ float4  s_w[G_Q][S_DIM][P_DIM][H_DIM];     // 12 KB
    __shared__ ushort4 s_pix[G_Q][S_DIM][P_DIM][H_DIM];   // 6 KB
    __shared__ int     s_mask[G_Q][S_DIM];
    __shared__ float   s_inv[G_Q];

    // ---- loads + softmax (no inter-thread deps before sync)
    {
        const int g = t >> 6, j = t & 63;
        s_off[g][j] = off_raw[(size_t)(n0 + g) * 64 + j];
    }
    if (t < G_Q * S_DIM) {   // 24
        const int g = t / S_DIM, s = t - g * S_DIM;
        const int n = n0 + g;
        const int* ss32 = (const int*)sshapes;
        const bool i32mode = (ss32[1] == WF);
        int mk;
        if (i32mode) {
            const int* bm = (const int*)bev_mask + ((size_t)s * N_DIM + n) * 4;
            mk = (bm[0] | bm[1] | bm[2] | bm[3]) ? 1 : 0;
        } else {
            const unsigned char* bm =
                (const unsigned char*)bev_mask + ((size_t)s * N_DIM + n) * 4;
            mk = (bm[0] | bm[1] | bm[2] | bm[3]) ? 1 : 0;
        }
        s_mask[g][s] = mk;
    }
    if (t < 128) {           // softmax over groups of 8 (direct global load)
        const int g = t >> 5, hp = t & 31;
        const float v = logits[(size_t)(n0 + g) * 32 + hp];
        float m = v;
        for (int d = 1; d < 8; d <<= 1) m = fmaxf(m, __shfl_xor(m, d, 8));
        const float e = expf(v - m);
        float sum = e;
        for (int d = 1; d < 8; d <<= 1) sum += __shfl_xor(sum, d, 8);
        s_attw[g][hp] = e / sum;
    }
    __syncthreads();
    if (t < G_Q) {
        int c = 0;
#pragma unroll
        for (int s = 0; s < S_DIM; ++s) c += s_mask[t][s];
        s_inv[t] = 1.f / fmaxf((float)c, 1.f);
    }

    // ---- precompute: per-(g,s,p,h) folded weights + pixel indices
    for (int i = t; i < G_Q * NENT; i += 256) {
        const int g = i / NENT;
        const int e = i - g * NENT;      // [0,192)
        const int s = e >> 5;
        const int rem = e & 31;          // p*4 + h
        const int p = rem >> 2, h = rem & 3;
        const int hp = h * P_DIM + p;
        const int d = p & 3;
        const int n = n0 + g;

        const float aw = s_attw[g][hp];
        const float offx = s_off[g][hp * 2 + 0] / (float)WF;
        const float offy = s_off[g][hp * 2 + 1] / (float)HF;
        const float refx = refpts[(((size_t)s * N_DIM + n) * 4 + d) * 2 + 0];
        const float refy = refpts[(((size_t)s * N_DIM + n) * 4 + d) * 2 + 1];

        const float x = (refx + offx) * (float)WF - 0.5f;
        const float y = (refy + offy) * (float)HF - 0.5f;
        const float x0f = floorf(x), y0f = floorf(y);
        const float lx = x - x0f, ly = y - y0f;
        const int x0 = (int)x0f, y0 = (int)y0f;
        const int x1 = x0 + 1, y1 = y0 + 1;

        const bool vx0 = (x0 >= 0) & (x0 < WF);
        const bool vx1 = (x1 >= 0) & (x1 < WF);
        const bool vy0 = (y0 >= 0) & (y0 < HF);
        const bool vy1 = (y1 >= 0) & (y1 < HF);

        const int cx0 = min(max(x0, 0), WF - 1);
        const int cx1 = min(max(x1, 0), WF - 1);
        const int cy0 = min(max(y0, 0), HF - 1);
        const int cy1 = min(max(y1, 0), HF - 1);

        s_pix[g][s][p][h] = make_ushort4(
            (unsigned short)(cy0 * WF + cx0),
            (unsigned short)(cy0 * WF + cx1),
            (unsigned short)(cy1 * WF + cx0),
            (unsigned short)(cy1 * WF + cx1));

        const float wx0 = 1.f - lx, wy0 = 1.f - ly;
        s_w[g][s][p][h] = make_float4((vx0 & vy0) ? wx0 * wy0 * aw : 0.f,
                                      (vx1 & vy0) ? lx  * wy0 * aw : 0.f,
                                      (vx0 & vy1) ? wx0 * ly  * aw : 0.f,
                                      (vx1 & vy1) ? lx  * ly  * aw : 0.f);
    }
    __syncthreads();

    // ---- gather: wave = 1 query, 16 lanes/head, 2 dh per lane
    {
        const char* vb = (const char*)vhw;
        const int g = t >> 6;
        const int lane = t & 63;
        const int h = lane >> 4;
        const int dhp4 = (lane & 15) * 4;
        float accx = 0.f, accy = 0.f;

        for (int s = 0; s < S_DIM; ++s) {
            if (!s_mask[g][s]) continue;
            const int base = ((s * H_DIM + h) * M_DIM) * 64 + dhp4;
#pragma unroll
            for (int pg = 0; pg < 4; ++pg) {
                const ushort4 p0 = s_pix[g][s][pg * 2 + 0][h];
                const ushort4 p1 = s_pix[g][s][pg * 2 + 1][h];
                const unsigned u0 = *(const unsigned*)(vb + base + (int)p0.x * 64);
                const unsigned u1 = *(const unsigned*)(vb + base + (int)p0.y * 64);
                const unsigned u2 = *(const unsigned*)(vb + base + (int)p0.z * 64);
                const unsigned u3 = *(const unsigned*)(vb + base + (int)p0.w * 64);
                const unsigned u4 = *(const unsigned*)(vb + base + (int)p1.x * 64);
                const unsigned u5 = *(const unsigned*)(vb + base + (int)p1.y * 64);
                const unsigned u6 = *(const unsigned*)(vb + base + (int)p1.z * 64);
                const unsigned u7 = *(const unsigned*)(vb + base + (int)p1.w * 64);
                const float4 w0 = s_w[g][s][pg * 2 + 0][h];
                const float4 w1 = s_w[g][s][pg * 2 + 1][h];
                accx = fmaf(w0.x, bfl(u0), accx); accy = fmaf(w0.x, bfh(u0), accy);
                accx = fmaf(w0.y, bfl(u1), accx); accy = fmaf(w0.y, bfh(u1), accy);
                accx = fmaf(w0.z, bfl(u2), accx); accy = fmaf(w0.z, bfh(u2), accy);
                accx = fmaf(w0.w, bfl(u3), accx); accy = fmaf(w0.w, bfh(u3), accy);
                accx = fmaf(w1.x, bfl(u4), accx); accy = fmaf(w1.x, bfh(u4), accy);
                accx = fmaf(w1.y, bfl(u5), accx); accy = fmaf(w1.y, bfh(u5), accy);
                accx = fmaf(w1.z, bfl(u6), accx); accy = fmaf(w1.z, bfh(u6), accy);
                accx = fmaf(w1.w, bfl(u7), accx); accy = fmaf(w1.w, bfh(u7), accy);
            }
        }
        const float inv = s_inv[g];
        const unsigned short o0 = f2bf(accx * inv);
        const unsigned short o1 = f2bf(accy * inv);
        const unsigned ow = (unsigned)o0 | ((unsigned)o1 << 16);
        *(unsigned*)&slots[(size_t)(n0 + g) * C_DIM + h * 32 + (lane & 15) * 2] = ow;
    }
}

// ---------------------------------------------------------------- K4 oproj
__global__ __launch_bounds__(256) void oproj_kernel(
    const unsigned short* __restrict__ slots,   // (N,C) bf16
    const float* __restrict__ Wp, const float* __restrict__ bp,
    const float* __restrict__ query,
    float* __restrict__ out)                    // (N,C)
{
    const int row0 = blockIdx.x * 64;
    const int t = threadIdx.x;
    const int tc = t & 31, tr = t >> 5;
    const int c0 = tc * 4, r0 = tr * 8;
    __shared__ float ss[64][C_DIM];

    for (int i = t; i < 64 * 32; i += 256) {
        const int row = i >> 5, c4 = (i & 31) * 4;
        int rr = row0 + row; if (rr >= N_DIM) rr = N_DIM - 1;
        const ushort4 u = *(const ushort4*)&slots[(size_t)rr * C_DIM + c4];
        float4 q; q.x = bf1(u.x); q.y = bf1(u.y); q.z = bf1(u.z); q.w = bf1(u.w);
        *(float4*)&ss[row][c4] = q;
    }
    __syncthreads();

    float acc[8][4];
#pragma unroll
    for (int r = 0; r < 8; ++r)
#pragma unroll
        for (int c = 0; c < 4; ++c) acc[r][c] = 0.f;

    for (int k = 0; k < C_DIM; k += 4) {
        const float4 w0 = *(const float4*)&Wp[(k + 0) * C_DIM + c0];
        const float4 w1 = *(const float4*)&Wp[(k + 1) * C_DIM + c0];
        const float4 w2 = *(const float4*)&Wp[(k + 2) * C_DIM + c0];
        const float4 w3 = *(const float4*)&Wp[(k + 3) * C_DIM + c0];
#pragma unroll
        for (int r = 0; r < 8; ++r) {
            const float4 v = *(const float4*)&ss[r0 + r][k];
            acc[r][0] = fmaf(v.x, w0.x, acc[r][0]);
            acc[r][0] = fmaf(v.y, w1.x, acc[r][0]);
            acc[r][0] = fmaf(v.z, w2.x, acc[r][0]);
            acc[r][0] = fmaf(v.w, w3.x, acc[r][0]);
            acc[r][1] = fmaf(v.x, w0.y, acc[r][1]);
            acc[r][1] = fmaf(v.y, w1.y, acc[r][1]);
            acc[r][1] = fmaf(v.z, w2.y, acc[r][1]);
            acc[r][1] = fmaf(v.w, w3.y, acc[r][1]);
            acc[r][2] = fmaf(v.x, w0.z, acc[r][2]);
            acc[r][2] = fmaf(v.y, w1.z, acc[r][2]);
            acc[r][2] = fmaf(v.z, w2.z, acc[r][2]);
            acc[r][2] = fmaf(v.w, w3.z, acc[r][2]);
            acc[r][3] = fmaf(v.x, w0.w, acc[r][3]);
            acc[r][3] = fmaf(v.y, w1.w, acc[r][3]);
            acc[r][3] = fmaf(v.z, w2.w, acc[r][3]);
            acc[r][3] = fmaf(v.w, w3.w, acc[r][3]);
        }
    }

    const float4 bb = *(const float4*)&bp[c0];
#pragma unroll
    for (int r = 0; r < 8; ++r) {
        const int row = row0 + r0 + r;
        if (row >= N_DIM) continue;
        const float4 q = *(const float4*)&query[(size_t)row * C_DIM + c0];
        float4 o;
        o.x = acc[r][0] + bb.x + q.x;
        o.y = acc[r][1] + bb.y + q.y;
        o.z = acc[r][2] + bb.z + q.z;
        o.w = acc[r][3] + bb.w + q.w;
        *(float4*)&out[(size_t)row * C_DIM + c0] = o;
    }
}

// ---------------------------------------------------------------- launch
extern "C" void kernel_launch(void* const* d_in, const int* in_sizes, int n_in,
                              void* d_out, int out_size, void* d_ws, size_t ws_size,
                              hipStream_t stream) {
    const float* query     = (const float*)d_in[0];
    // d_in[1] = key (unused by reference)
    const float* value     = (const float*)d_in[2];
    const float* query_pos = (const float*)d_in[3];
    const float* refpts    = (const float*)d_in[4];
    const float* Wv        = (const float*)d_in[5];
    const float* bv        = (const float*)d_in[6];
    const float* Wo        = (const float*)d_in[7];
    const float* bo        = (const float*)d_in[8];
    const float* Wa        = (const float*)d_in[9];
    const float* ba        = (const float*)d_in[10];
    const float* Wp        = (const float*)d_in[11];
    const float* bp        = (const float*)d_in[12];
    const void*  sshapes   = d_in[13];
    const void*  bev_mask  = d_in[14];

    unsigned short* vhw     = (unsigned short*)d_ws;
    float*          off_raw = (float*)(vhw + VHW_SHORTS);
    float*          lg      = off_raw + (size_t)N_DIM * 64;
    unsigned short* slots   = (unsigned short*)(lg + (size_t)N_DIM * 32);
    float*          outp    = (float*)d_out;

    hipLaunchKernelGGL(vproj_kernel, dim3((S_DIM * M_DIM) / 64), dim3(256), 0, stream,
                       value, Wv, bv, vhw);
    hipLaunchKernelGGL(qproj_kernel, dim3((N_DIM + 63) / 64), dim3(256), 0, stream,
                       query, query_pos, Wo, bo, Wa, ba, off_raw, lg);
    hipLaunchKernelGGL(attn_kernel, dim3(N_DIM / G_Q), dim3(256), 0, stream,
                       vhw, off_raw, lg, refpts, bev_mask, sshapes, slots);
    hipLaunchKernelGGL(oproj_kernel, dim3((N_DIM + 63) / 64), dim3(256), 0, stream,
                       slots, Wp, bp, query, outp);
}

// Round 7
// 78.267 us; speedup vs baseline: 1.3038x; 1.3038x over previous
//
#include <hip/hip_runtime.h>

// SpatialCrossAttention (BEVFormer) — 2 kernels:
//  A) vproj : value @ Wv + bv -> vhw bf16 (register-tiled 32-row GEMM)
//  B) attn  : fused qproj + per-(g,s,p,h) weight/offset precompute +
//             dword-pair bf16 gather (wave = 1 query, 2 dh per lane) + @Wp + residual

#define S_DIM 6
#define N_DIM 10000
#define C_DIM 128
#define M_DIM 3680
#define H_DIM 4
#define P_DIM 8
#define DH    32
#define HF    46
#define WF    80

#define G_Q   4
#define NENT  (S_DIM * P_DIM * H_DIM)             // 192
#define VHW_SHORTS (S_DIM * H_DIM * M_DIM * DH)   // 2,826,240

__device__ __forceinline__ float bfl(unsigned u) { return __uint_as_float(u << 16); }
__device__ __forceinline__ float bfh(unsigned u) { return __uint_as_float(u & 0xffff0000u); }
__device__ __forceinline__ unsigned short f2bf(float f) {
    unsigned b = __float_as_uint(f);
    b += 0x7FFFu + ((b >> 16) & 1u);   // RNE
    return (unsigned short)(b >> 16);
}

// ---------------------------------------------------------------- kernel A
// 32 rows/block, 256 threads: thread tile = 4 rows x 4 cols.
__global__ __launch_bounds__(256) void vproj_kernel(
    const float* __restrict__ value,   // (S*M, C)
    const float* __restrict__ Wv,      // (C, C)
    const float* __restrict__ bv,      // (C)
    unsigned short* __restrict__ vhw)  // (S, H, M, DH) bf16
{
    const int row0 = blockIdx.x * 32;
    const int t = threadIdx.x;
    const int tc = t & 31, tr = t >> 5;   // tr in [0,8)
    const int c0 = tc * 4, r0 = tr * 4;
    __shared__ float vs[32][C_DIM];       // 16 KB

    for (int i = t; i < 32 * 32; i += 256) {
        const int row = i >> 5, c4 = (i & 31) * 4;
        *(float4*)&vs[row][c4] =
            *(const float4*)&value[(size_t)(row0 + row) * C_DIM + c4];
    }
    __syncthreads();

    float acc[4][4];
#pragma unroll
    for (int r = 0; r < 4; ++r)
#pragma unroll
        for (int c = 0; c < 4; ++c) acc[r][c] = 0.f;

    for (int k = 0; k < C_DIM; k += 4) {
        const float4 w0 = *(const float4*)&Wv[(k + 0) * C_DIM + c0];
        const float4 w1 = *(const float4*)&Wv[(k + 1) * C_DIM + c0];
        const float4 w2 = *(const float4*)&Wv[(k + 2) * C_DIM + c0];
        const float4 w3 = *(const float4*)&Wv[(k + 3) * C_DIM + c0];
#pragma unroll
        for (int r = 0; r < 4; ++r) {
            const float4 v = *(const float4*)&vs[r0 + r][k];
            acc[r][0] = fmaf(v.x, w0.x, acc[r][0]);
            acc[r][0] = fmaf(v.y, w1.x, acc[r][0]);
            acc[r][0] = fmaf(v.z, w2.x, acc[r][0]);
            acc[r][0] = fmaf(v.w, w3.x, acc[r][0]);
            acc[r][1] = fmaf(v.x, w0.y, acc[r][1]);
            acc[r][1] = fmaf(v.y, w1.y, acc[r][1]);
            acc[r][1] = fmaf(v.z, w2.y, acc[r][1]);
            acc[r][1] = fmaf(v.w, w3.y, acc[r][1]);
            acc[r][2] = fmaf(v.x, w0.z, acc[r][2]);
            acc[r][2] = fmaf(v.y, w1.z, acc[r][2]);
            acc[r][2] = fmaf(v.z, w2.z, acc[r][2]);
            acc[r][2] = fmaf(v.w, w3.z, acc[r][2]);
            acc[r][3] = fmaf(v.x, w0.w, acc[r][3]);
            acc[r][3] = fmaf(v.y, w1.w, acc[r][3]);
            acc[r][3] = fmaf(v.z, w2.w, acc[r][3]);
            acc[r][3] = fmaf(v.w, w3.w, acc[r][3]);
        }
    }

    const float4 bb = *(const float4*)&bv[c0];
    const int h = c0 >> 5, dh0 = c0 & 31;
#pragma unroll
    for (int r = 0; r < 4; ++r) {
        const int row = row0 + r0 + r;
        const int s = row / M_DIM, m = row - s * M_DIM;
        ushort4 o;
        o.x = f2bf(acc[r][0] + bb.x);
        o.y = f2bf(acc[r][1] + bb.y);
        o.z = f2bf(acc[r][2] + bb.z);
        o.w = f2bf(acc[r][3] + bb.w);
        *(ushort4*)&vhw[(((size_t)s * H_DIM + h) * M_DIM + m) * DH + dh0] = o;
    }
}

// ---------------------------------------------------------------- kernel B
__global__ __launch_bounds__(256, 4) void attn_kernel(
    const unsigned short* __restrict__ vhw,   // (S,H,M,DH) bf16
    const float* __restrict__ query,
    const float* __restrict__ query_pos,
    const float* __restrict__ Wo, const float* __restrict__ bo,   // (C,64),(64)
    const float* __restrict__ Wa, const float* __restrict__ ba,   // (C,32),(32)
    const float* __restrict__ refpts,   // (S,1,N,4,2)
    const void* __restrict__ bev_mask,  // (S,1,N,4) bool/int32
    const void* __restrict__ sshapes,   // int probe
    const float* __restrict__ Wp, const float* __restrict__ bp,
    float* __restrict__ out)            // (1,N,C)
{
    const int n0 = blockIdx.x * G_Q;
    const int t = threadIdx.x;          // 256

    __shared__ float  qs[G_Q][C_DIM];                    // 2 KB
    __shared__ float  s_offr[G_Q][64];                   // 1 KB
    __shared__ float  s_ar[G_Q][32];
    __shared__ float  s_attw[G_Q][32];
    __shared__ int4   s_o[G_Q][S_DIM][P_DIM][H_DIM];     // 12 KB  [g][s][p][h]
    __shared__ float4 s_w[G_Q][S_DIM][P_DIM][H_DIM];     // 12 KB
    __shared__ float  s_slots[G_Q][C_DIM];               // 2 KB
    __shared__ int    s_mask[G_Q][S_DIM];
    __shared__ float  s_inv[G_Q];

    // ---- phase 0: queries + masks
    for (int i = t; i < G_Q * C_DIM; i += 256) {
        const int g = i >> 7, c = i & 127;
        const size_t a = (size_t)(n0 + g) * C_DIM + c;
        qs[g][c] = query[a] + query_pos[a];
    }
    if (t < G_Q * S_DIM) {   // 24
        const int g = t / S_DIM, s = t - g * S_DIM;
        const int n = n0 + g;
        const int* ss32 = (const int*)sshapes;
        const bool i32mode = (ss32[1] == WF);
        int mk;
        if (i32mode) {
            const int* bm = (const int*)bev_mask + ((size_t)s * N_DIM + n) * 4;
            mk = (bm[0] | bm[1] | bm[2] | bm[3]) ? 1 : 0;
        } else {
            const unsigned char* bm =
                (const unsigned char*)bev_mask + ((size_t)s * N_DIM + n) * 4;
            mk = (bm[0] | bm[1] | bm[2] | bm[3]) ? 1 : 0;
        }
        s_mask[g][s] = mk;
    }
    __syncthreads();
    if (t < G_Q) {
        int c = 0;
#pragma unroll
        for (int s = 0; s < S_DIM; ++s) c += s_mask[t][s];
        s_inv[t] = 1.f / fmaxf((float)c, 1.f);
    }

    // ---- phase 1: fused qproj
    {   // offsets: all 256 threads, g = t>>6, j = t&63
        const int g = t >> 6, j = t & 63;
        float acc = 0.f;
        for (int k = 0; k < C_DIM; k += 4) {
            const float4 q4 = *(const float4*)&qs[g][k];
            acc = fmaf(q4.x, Wo[(k + 0) * 64 + j], acc);
            acc = fmaf(q4.y, Wo[(k + 1) * 64 + j], acc);
            acc = fmaf(q4.z, Wo[(k + 2) * 64 + j], acc);
            acc = fmaf(q4.w, Wo[(k + 3) * 64 + j], acc);
        }
        s_offr[g][j] = acc + bo[j];
    }
    if (t < G_Q * 32) {   // attn logits: g = t>>5, jj = t&31
        const int g = t >> 5, jj = t & 31;
        float acc = 0.f;
        for (int k = 0; k < C_DIM; k += 4) {
            const float4 q4 = *(const float4*)&qs[g][k];
            acc = fmaf(q4.x, Wa[(k + 0) * 32 + jj], acc);
            acc = fmaf(q4.y, Wa[(k + 1) * 32 + jj], acc);
            acc = fmaf(q4.z, Wa[(k + 2) * 32 + jj], acc);
            acc = fmaf(q4.w, Wa[(k + 3) * 32 + jj], acc);
        }
        s_ar[g][jj] = acc + ba[jj];
    }
    __syncthreads();
    if (t < G_Q * 32) {   // softmax over groups of 8
        const int g = t >> 5, hp = t & 31;
        const float v = s_ar[g][hp];
        float m = v;
        for (int d = 1; d < 8; d <<= 1) m = fmaxf(m, __shfl_xor(m, d, 8));
        const float e = expf(v - m);
        float sum = e;
        for (int d = 1; d < 8; d <<= 1) sum += __shfl_xor(sum, d, 8);
        s_attw[g][hp] = e / sum;
    }
    __syncthreads();

    // ---- phase 1b: per-(g,s,p,h) weights + byte offsets (768 entries)
    for (int i = t; i < G_Q * NENT; i += 256) {
        const int g = i / NENT;
        const int e = i - g * NENT;      // e in [0,192)
        const int s = e >> 5;
        const int rem = e & 31;          // p*4 + h
        const int p = rem >> 2, h = rem & 3;
        const int hp = h * P_DIM + p;
        const int d = p & 3;
        const int n = n0 + g;

        const float aw = s_attw[g][hp];
        const float offx = s_offr[g][hp * 2 + 0] / (float)WF;
        const float offy = s_offr[g][hp * 2 + 1] / (float)HF;
        const float refx = refpts[(((size_t)s * N_DIM + n) * 4 + d) * 2 + 0];
        const float refy = refpts[(((size_t)s * N_DIM + n) * 4 + d) * 2 + 1];

        const float x = (refx + offx) * (float)WF - 0.5f;
        const float y = (refy + offy) * (float)HF - 0.5f;
        const float x0f = floorf(x), y0f = floorf(y);
        const float lx = x - x0f, ly = y - y0f;
        const int x0 = (int)x0f, y0 = (int)y0f;
        const int x1 = x0 + 1, y1 = y0 + 1;

        const bool vx0 = (x0 >= 0) & (x0 < WF);
        const bool vx1 = (x1 >= 0) & (x1 < WF);
        const bool vy0 = (y0 >= 0) & (y0 < HF);
        const bool vy1 = (y1 >= 0) & (y1 < HF);

        const int cx0 = min(max(x0, 0), WF - 1);
        const int cx1 = min(max(x1, 0), WF - 1);
        const int cy0 = min(max(y0, 0), HF - 1);
        const int cy1 = min(max(y1, 0), HF - 1);

        const int base = (s * H_DIM + h) * M_DIM;
        const int r0 = base + cy0 * WF;
        const int r1 = base + cy1 * WF;
        s_o[g][s][p][h] = make_int4((r0 + cx0) * (DH * 2),
                                    (r0 + cx1) * (DH * 2),
                                    (r1 + cx0) * (DH * 2),
                                    (r1 + cx1) * (DH * 2));

        const float wx0 = 1.f - lx, wy0 = 1.f - ly;
        s_w[g][s][p][h] = make_float4((vx0 & vy0) ? wx0 * wy0 * aw : 0.f,
                                      (vx1 & vy0) ? lx  * wy0 * aw : 0.f,
                                      (vx0 & vy1) ? wx0 * ly  * aw : 0.f,
                                      (vx1 & vy1) ? lx  * ly  * aw : 0.f);
    }
    __syncthreads();

    // ---- phase 2: gather — wave = 1 query, 16 lanes/head, 2 dh per lane
    {
        const char* vb = (const char*)vhw;
        const int g = t >> 6;
        const int lane = t & 63;
        const int h = lane >> 4;
        const int dhp4 = (lane & 15) * 4;   // byte offset of the dh pair
        float accx = 0.f, accy = 0.f;

        for (int s = 0; s < S_DIM; ++s) {
            if (!s_mask[g][s]) continue;
#pragma unroll
            for (int pg = 0; pg < 4; ++pg) {
                const int4 o0 = s_o[g][s][pg * 2 + 0][h];
                const int4 o1 = s_o[g][s][pg * 2 + 1][h];
                unsigned u0 = *(const unsigned*)(vb + (o0.x + dhp4));
                unsigned u1 = *(const unsigned*)(vb + (o0.y + dhp4));
                unsigned u2 = *(const unsigned*)(vb + (o0.z + dhp4));
                unsigned u3 = *(const unsigned*)(vb + (o0.w + dhp4));
                unsigned u4 = *(const unsigned*)(vb + (o1.x + dhp4));
                unsigned u5 = *(const unsigned*)(vb + (o1.y + dhp4));
                unsigned u6 = *(const unsigned*)(vb + (o1.z + dhp4));
                unsigned u7 = *(const unsigned*)(vb + (o1.w + dhp4));
                const float4 w0 = s_w[g][s][pg * 2 + 0][h];
                const float4 w1 = s_w[g][s][pg * 2 + 1][h];
                accx = fmaf(w0.x, bfl(u0), accx); accy = fmaf(w0.x, bfh(u0), accy);
                accx = fmaf(w0.y, bfl(u1), accx); accy = fmaf(w0.y, bfh(u1), accy);
                accx = fmaf(w0.z, bfl(u2), accx); accy = fmaf(w0.z, bfh(u2), accy);
                accx = fmaf(w0.w, bfl(u3), accx); accy = fmaf(w0.w, bfh(u3), accy);
                accx = fmaf(w1.x, bfl(u4), accx); accy = fmaf(w1.x, bfh(u4), accy);
                accx = fmaf(w1.y, bfl(u5), accx); accy = fmaf(w1.y, bfh(u5), accy);
                accx = fmaf(w1.z, bfl(u6), accx); accy = fmaf(w1.z, bfh(u6), accy);
                accx = fmaf(w1.w, bfl(u7), accx); accy = fmaf(w1.w, bfh(u7), accy);
            }
        }
        const float inv = s_inv[g];
        *(float2*)&s_slots[g][h * 32 + (lane & 15) * 2] =
            make_float2(accx * inv, accy * inv);
    }
    __syncthreads();

    // ---- phase 3: out projection + bias + residual (Wp read 2x/block)
    {
        const int c = t & 127, half = t >> 7;
        const int g0 = half * 2;
        float a0 = 0.f, a1 = 0.f;
        for (int k = 0; k < C_DIM; k += 4) {
            const float4 s0 = *(const float4*)&s_slots[g0][k];
            const float4 s1 = *(const float4*)&s_slots[g0 + 1][k];
            const float w0 = Wp[(k + 0) * C_DIM + c];
            const float w1 = Wp[(k + 1) * C_DIM + c];
            const float w2 = Wp[(k + 2) * C_DIM + c];
            const float w3 = Wp[(k + 3) * C_DIM + c];
            a0 = fmaf(s0.x, w0, a0); a1 = fmaf(s1.x, w0, a1);
            a0 = fmaf(s0.y, w1, a0); a1 = fmaf(s1.y, w1, a1);
            a0 = fmaf(s0.z, w2, a0); a1 = fmaf(s1.z, w2, a1);
            a0 = fmaf(s0.w, w3, a0); a1 = fmaf(s1.w, w3, a1);
        }
        const int na = n0 + g0;
        const float bb = bp[c];
        out[(size_t)na * C_DIM + c]       = a0 + bb + query[(size_t)na * C_DIM + c];
        out[(size_t)(na + 1) * C_DIM + c] = a1 + bb + query[(size_t)(na + 1) * C_DIM + c];
    }
}

// ---------------------------------------------------------------- launch
extern "C" void kernel_launch(void* const* d_in, const int* in_sizes, int n_in,
                              void* d_out, int out_size, void* d_ws, size_t ws_size,
                              hipStream_t stream) {
    const float* query     = (const float*)d_in[0];
    // d_in[1] = key (unused by reference)
    const float* value     = (const float*)d_in[2];
    const float* query_pos = (const float*)d_in[3];
    const float* refpts    = (const float*)d_in[4];
    const float* Wv        = (const float*)d_in[5];
    const float* bv        = (const float*)d_in[6];
    const float* Wo        = (const float*)d_in[7];
    const float* bo        = (const float*)d_in[8];
    const float* Wa        = (const float*)d_in[9];
    const float* ba        = (const float*)d_in[10];
    const float* Wp        = (const float*)d_in[11];
    const float* bp        = (const float*)d_in[12];
    const void*  sshapes   = d_in[13];
    const void*  bev_mask  = d_in[14];

    unsigned short* vhw = (unsigned short*)d_ws;
    float* outp = (float*)d_out;

    hipLaunchKernelGGL(vproj_kernel, dim3((S_DIM * M_DIM) / 32), dim3(256), 0, stream,
                       value, Wv, bv, vhw);
    hipLaunchKernelGGL(attn_kernel, dim3(N_DIM / G_Q), dim3(256), 0, stream,
                       vhw, query, query_pos, Wo, bo, Wa, ba,
                       refpts, bev_mask, sshapes, Wp, bp, outp);
}